// Round 8
// baseline (793.663 us; speedup 1.0000x reference)
//
#include <hip/hip_runtime.h>
#include <hip/hip_bf16.h>

#define D 128

typedef unsigned short u16;
typedef unsigned int   u32;
typedef unsigned long long u64;
typedef short bf16x8 __attribute__((ext_vector_type(8)));
typedef float f32x4  __attribute__((ext_vector_type(4)));

__device__ __forceinline__ float bf2f(u16 u) {
    union { u32 i; float f; } v; v.i = ((u32)u) << 16; return v.f;
}
__device__ __forceinline__ float bflo(u32 p) {
    union { u32 i; float f; } v; v.i = p << 16; return v.f;
}
__device__ __forceinline__ float bfhi(u32 p) {
    union { u32 i; float f; } v; v.i = p & 0xffff0000u; return v.f;
}
__device__ __forceinline__ u16 f2bf(float f) {
    union { float f; u32 i; } v; v.f = f;
    return (u16)((v.i + 0x7fffu + ((v.i >> 16) & 1u)) >> 16);
}
__device__ __forceinline__ float ldf(const void* p, long i, int isb) {
    return isb ? bf2f(((const u16*)p)[i]) : ((const float*)p)[i];
}

__device__ __forceinline__ float sigm(float x) { return 1.0f / (1.0f + __expf(-x)); }
__device__ __forceinline__ float tanh_fast(float x) {
    float a = fabsf(x);
    float t = __expf(-2.0f * a);
    float r = (1.0f - t) / (1.0f + t);
    return copysignf(r, x);
}

__global__ void DRlocal_net_79173427135059_kernel() {}

// K-1: runtime dtype detection + zero the bucket histogram.
__global__ __launch_bounds__(64) void k_detect(const void* ent, const void* nid,
                                               int* flag, int* bhist) {
    int lane = threadIdx.x;
    for (int i = lane; i < 512; i += 64) bhist[i] = 0;
    float a = fabsf(bf2f(((const u16*)ent)[lane]));
    bool sane = (a >= 9.765625e-4f && a <= 64.0f);
    u64 m = __ballot(sane);
    u32 w = ((const u32*)nid)[lane];
    bool oddzero = ((lane & 1) == 0) || (w == 0u);
    u64 m2 = __ballot(oddzero);
    if (lane == 0) {
        flag[0] = (__popcll(m) >= 48) ? 1 : 0;
        flag[1] = (m2 == ~0ull) ? 1 : 0;
    }
}

// K0: WTb[j][k] = bf16(W[k][j]); GRU weights -> bf16 as-is; biases -> f32.
__global__ __launch_bounds__(256) void k_prep(
    const void* __restrict__ w_ih, const void* __restrict__ w_hh,
    const void* __restrict__ b_ih, const void* __restrict__ b_hh,
    const void* __restrict__ W, const int* __restrict__ flag,
    u16* __restrict__ WTb, u16* __restrict__ Wihb, u16* __restrict__ Whhb,
    float* __restrict__ bif, float* __restrict__ bhf)
{
    int isb = flag[0];
    int t = blockIdx.x * 256 + threadIdx.x;
    if (t < 16384) {
        int k = t >> 7, j = t & 127;
        u16 v = isb ? ((const u16*)W)[t] : f2bf(((const float*)W)[t]);
        WTb[j * 128 + k] = v;
        return;
    }
    int u = t - 16384;
    if (u < 98304) { Wihb[u] = isb ? ((const u16*)w_ih)[u] : f2bf(((const float*)w_ih)[u]); return; }
    int v = u - 98304;
    if (v < 49152) { Whhb[v] = isb ? ((const u16*)w_hh)[v] : f2bf(((const float*)w_hh)[v]); return; }
    int b = v - 49152;
    if (b < 384) { bif[b] = ldf(b_ih, b, isb); return; }
    int c = b - 384;
    if (c < 384) { bhf[c] = ldf(b_hh, c, isb); return; }
}

// K1: hW = gather(ent, node_id) @ W via MFMA. 64 nodes/block, wave = one 16-row m-tile.
__global__ __launch_bounds__(256) void k_gmm_mfma(
    const void* __restrict__ ent, const void* __restrict__ node_id,
    const u16* __restrict__ WTb, u16* __restrict__ hW,
    const int* __restrict__ flag, int N)
{
    int isb = flag[0], i64 = flag[1];
    int tid = threadIdx.x;
    int wave = tid >> 6, lane = tid & 63;
    int qm = lane >> 4, qr = lane & 15;
    int row0 = blockIdx.x * 64 + wave * 16;

    int rowA = row0 + qr; if (rowA >= N) rowA = N - 1;
    long nid = i64 ? (long)((const long long*)node_id)[rowA]
                   : (long)((const int*)node_id)[rowA];

    bf16x8 a[4];
    if (isb) {
        const u16* ep = (const u16*)ent + nid * 128 + qm * 8;
        #pragma unroll
        for (int s = 0; s < 4; ++s) a[s] = *(const bf16x8*)(ep + s * 32);
    } else {
        const float* ep = (const float*)ent + nid * 128 + qm * 8;
        #pragma unroll
        for (int s = 0; s < 4; ++s) {
            float4 f0 = *(const float4*)(ep + s * 32);
            float4 f1 = *(const float4*)(ep + s * 32 + 4);
            bf16x8 t;
            t[0] = (short)f2bf(f0.x); t[1] = (short)f2bf(f0.y);
            t[2] = (short)f2bf(f0.z); t[3] = (short)f2bf(f0.w);
            t[4] = (short)f2bf(f1.x); t[5] = (short)f2bf(f1.y);
            t[6] = (short)f2bf(f1.z); t[7] = (short)f2bf(f1.w);
            a[s] = t;
        }
    }

    int r0 = row0 + qm * 4;
    #pragma unroll
    for (int f = 0; f < 8; ++f) {
        f32x4 acc = {0.f, 0.f, 0.f, 0.f};
        const u16* wp = WTb + (size_t)(f * 16 + qr) * 128 + qm * 8;
        #pragma unroll
        for (int s = 0; s < 4; ++s) {
            bf16x8 b = *(const bf16x8*)(wp + s * 32);
            acc = __builtin_amdgcn_mfma_f32_16x16x32_bf16(a[s], b, acc, 0, 0, 0);
        }
        int col = f * 16 + qr;
        #pragma unroll
        for (int r = 0; r < 4; ++r) {
            int row = r0 + r;
            if (row < N) hW[(size_t)row * 128 + col] = f2bf(acc[r]);
        }
    }
}

// ---- Bucket CSR build ----
__global__ __launch_bounds__(256) void k_bhist(
    const int* __restrict__ edst, int* __restrict__ bhist,
    int E, int NB, int bshift)
{
    __shared__ int lcnt[512];
    int t = threadIdx.x;
    int e0 = blockIdx.x * 8192;
    for (int i = t; i < NB; i += 256) lcnt[i] = 0;
    __syncthreads();
    for (int i = t; i < 8192; i += 256) {
        int e = e0 + i;
        if (e < E) atomicAdd(&lcnt[edst[e] >> bshift], 1);
    }
    __syncthreads();
    for (int i = t; i < NB; i += 256) {
        int c = lcnt[i];
        if (c) atomicAdd(&bhist[i], c);
    }
}

__global__ __launch_bounds__(512) void k_bscan(
    const int* __restrict__ bhist, int* __restrict__ bstart,
    int* __restrict__ bcur, int* __restrict__ rowstart,
    int NB, int N, int E)
{
    __shared__ int sh[512];
    int t = threadIdx.x;
    int v = (t < NB) ? bhist[t] : 0;
    sh[t] = v;
    __syncthreads();
    #pragma unroll
    for (int off = 1; off < 512; off <<= 1) {
        int x = (t >= off) ? sh[t - off] : 0;
        __syncthreads();
        sh[t] += x;
        __syncthreads();
    }
    int excl = sh[t] - v;
    if (t < NB) { bstart[t] = excl; bcur[t] = excl; }
    if (t == 0) { bstart[NB] = E; rowstart[N] = E; }
}

__global__ __launch_bounds__(256) void k_afill(
    const int* __restrict__ esrc, const int* __restrict__ edst,
    int* __restrict__ bcur, u64* __restrict__ ebuf,
    int E, int NB, int bshift)
{
    __shared__ int lcnt[512];
    int t = threadIdx.x;
    int e0 = blockIdx.x * 8192;
    for (int i = t; i < NB; i += 256) lcnt[i] = 0;
    __syncthreads();
    for (int i = t; i < 8192; i += 256) {
        int e = e0 + i;
        if (e < E) atomicAdd(&lcnt[edst[e] >> bshift], 1);
    }
    __syncthreads();
    for (int b = t; b < NB; b += 256) {
        int c = lcnt[b];
        lcnt[b] = c ? atomicAdd(&bcur[b], c) : 0;
    }
    __syncthreads();
    for (int i = t; i < 8192; i += 256) {
        int e = e0 + i;
        if (e < E) {
            int d = edst[e];
            int pos = atomicAdd(&lcnt[d >> bshift], 1);
            ebuf[pos] = ((u64)(u32)esrc[e] << 32) | (u32)d;
        }
    }
}

__global__ __launch_bounds__(256) void k_bfill(
    const u64* __restrict__ ebuf, const int* __restrict__ bstart,
    int* __restrict__ rowstart, int* __restrict__ sorted_src,
    int N, int bshift)
{
    __shared__ int lcnt[1024];
    __shared__ int lscan[256];
    int b = blockIdx.x, t = threadIdx.x;
    int nodes = 1 << bshift;
    int per = nodes >> 8;
    int base = b << bshift;
    int beg = bstart[b], end = bstart[b + 1];

    for (int i = t; i < nodes; i += 256) lcnt[i] = 0;
    __syncthreads();
    for (int i = beg + t; i < end; i += 256) {
        int d = (int)(u32)ebuf[i];
        atomicAdd(&lcnt[d - base], 1);
    }
    __syncthreads();

    int myv[4]; int mysum = 0;
    #pragma unroll
    for (int j = 0; j < 4; ++j) {
        myv[j] = (j < per) ? lcnt[t * per + j] : 0;
        mysum += myv[j];
    }
    lscan[t] = mysum;
    __syncthreads();
    #pragma unroll
    for (int off = 1; off < 256; off <<= 1) {
        int x = (t >= off) ? lscan[t - off] : 0;
        __syncthreads();
        lscan[t] += x;
        __syncthreads();
    }
    int run = beg + lscan[t] - mysum;
    #pragma unroll
    for (int j = 0; j < 4; ++j) {
        if (j < per) {
            int idx = t * per + j;
            int node = base + idx;
            if (node < N) rowstart[node] = run;
            lcnt[idx] = run;
            run += myv[j];
        }
    }
    __syncthreads();
    for (int i = beg + t; i < end; i += 256) {
        u64 p = ebuf[i];
        int d = (int)(u32)p;
        int pos = atomicAdd(&lcnt[d - base], 1);
        sorted_src[pos] = (int)(p >> 32);
    }
}

// K3 v2: column-sliced, XCD-pinned segment sum.
// slice = blockIdx % 8 -> 16 cols (3.2 MB of hW) pinned to one XCD's L2 via
// round-robin dispatch; the random edge gather becomes an L2 hit after warmup
// (was 290 MB of L3 re-fetch). Wave = 1 node, 8 edges x 8 u32-lanes per step;
// reduce across edge-groups via shfl_xor(8,16,32); lanes 0-7 write the 32 B
// X-slice + matching bias-slice.
__global__ __launch_bounds__(256) void k_seg(
    const u16* __restrict__ hW, const int* __restrict__ rowstart,
    const int* __restrict__ sorted_src, const void* __restrict__ onorm,
    const void* __restrict__ bias, u16* __restrict__ X,
    const int* __restrict__ flag, int N)
{
    int isb = flag[0];
    int tid = threadIdx.x;
    int wave = tid >> 6, lane = tid & 63;
    int le = lane >> 3;            // edge-parallel index 0..7
    int lc = lane & 7;             // u32 within the 16-col slice
    int sl = blockIdx.x & 7;       // slice -> XCD pin
    int ngrp = blockIdx.x >> 3;
    int u0 = sl * 8 + lc;          // u32 col index 0..63

    const u32* hw2 = (const u32*)hW;

    #pragma unroll 1
    for (int ni = wave; ni < 32; ni += 4) {
        int node = ngrp * 32 + ni;
        if (node >= N) break;
        int beg = rowstart[node], end = rowstart[node + 1];
        float a0 = 0.f, a1 = 0.f;
        for (int e = beg + le; e < end; e += 8) {
            int src = sorted_src[e];
            u32 v = hw2[(size_t)src * 64 + u0];
            a0 += bflo(v); a1 += bfhi(v);
        }
        // reduce over the 8 edge-groups (lane bits 3,4,5)
        a0 += __shfl_xor(a0, 8, 64);  a1 += __shfl_xor(a1, 8, 64);
        a0 += __shfl_xor(a0, 16, 64); a1 += __shfl_xor(a1, 16, 64);
        a0 += __shfl_xor(a0, 32, 64); a1 += __shfl_xor(a1, 32, 64);
        if (le == 0) {
            float on = ldf(onorm, node, isb);
            u32 p = ((u32)f2bf(a1 * on) << 16) | (u32)f2bf(a0 * on);
            ((u32*)X)[(size_t)node * 128 + u0] = p;
            u32 pb;
            if (isb) pb = ((const u32*)bias)[(size_t)node * 64 + u0];
            else {
                const float* bp = (const float*)bias + (size_t)node * 128 + u0 * 2;
                pb = ((u32)f2bf(bp[1]) << 16) | (u32)f2bf(bp[0]);
            }
            ((u32*)X)[(size_t)node * 128 + 64 + u0] = pb;
        }
    }
}

// K4 v6, pass 1: LDS-weight-resident MFMA GRU, column-split (unchanged, proven).
__global__ __launch_bounds__(512, 2) void k_gru_mfma(
    const u16* __restrict__ X, const u16* __restrict__ Wih,
    const u16* __restrict__ Whh, const float* __restrict__ bif,
    const float* __restrict__ bhf, void* __restrict__ out,
    float* __restrict__ ssb,
    const int* __restrict__ flag, int N, int NpadX)
{
    __shared__ alignas(16) char smem[147456];
    int isb = flag[0];
    int tid = threadIdx.x;
    int wave = tid >> 6, lane = tid & 63;
    int qm = lane >> 4, qr = lane & 15;
    int g = blockIdx.x & 1;
    int chunk = blockIdx.x >> 1;
    int g64 = g * 64;

    for (int t = tid; t < 6144; t += 512) {
        int L = t * 16;
        int kb = L & 511;
        int c  = (L >> 9) & 63;
        int gi = L >> 15;
        int src = (gi * 128 + g64 + c) * 512 + kb;
        int dst = L ^ ((c & 7) << 4);
        *(bf16x8*)(smem + dst) = *(const bf16x8*)((const char*)Wih + src);
    }
    for (int t = tid; t < 3072; t += 512) {
        int L = t * 16;
        int kb = L & 255;
        int c  = (L >> 8) & 63;
        int gi = L >> 14;
        int src = (gi * 128 + g64 + c) * 256 + kb;
        int dst = 98304 + (L ^ ((c & 7) << 4));
        *(bf16x8*)(smem + dst) = *(const bf16x8*)((const char*)Whh + src);
    }
    __syncthreads();

    int rbase = chunk * 256 + wave * 32;

    bf16x8 aA[8], aB[8];
    {
        const u16* x0 = X + (size_t)(rbase + qr) * 256 + qm * 8;
        #pragma unroll
        for (int s = 0; s < 8; ++s) aA[s] = *(const bf16x8*)(x0 + s * 32);
        const u16* x1 = x0 + 16 * 256;
        #pragma unroll
        for (int s = 0; s < 8; ++s) aB[s] = *(const bf16x8*)(x1 + s * 32);
    }

    float ss[8] = {0.f, 0.f, 0.f, 0.f, 0.f, 0.f, 0.f, 0.f};

    #pragma unroll 1
    for (int sl = 0; sl < 4; ++sl) {
        int colIdx = sl * 16 + qr;
        int colg = g64 + colIdx;
        int sw = (qr & 7) << 4;
        int cbI = colIdx * 512 + qm * 16;
        int cbH = colIdx * 256 + qm * 16;

        f32x4 zz = {0.f, 0.f, 0.f, 0.f};
        f32x4 aR0 = zz, aR1 = zz, aZ0 = zz, aZ1 = zz;
        f32x4 aN0 = zz, aN1 = zz, aH0 = zz, aH1 = zz;

        {   // r gate
            bf16x8 w[12];
            #pragma unroll
            for (int s = 0; s < 8; ++s)
                w[s] = *(const bf16x8*)(smem + ((cbI + s * 64) ^ sw));
            #pragma unroll
            for (int s = 0; s < 4; ++s)
                w[8 + s] = *(const bf16x8*)(smem + 98304 + ((cbH + s * 64) ^ sw));
            #pragma unroll
            for (int s = 0; s < 8; ++s) {
                aR0 = __builtin_amdgcn_mfma_f32_16x16x32_bf16(aA[s], w[s], aR0, 0, 0, 0);
                aR1 = __builtin_amdgcn_mfma_f32_16x16x32_bf16(aB[s], w[s], aR1, 0, 0, 0);
            }
            #pragma unroll
            for (int s = 0; s < 4; ++s) {
                aR0 = __builtin_amdgcn_mfma_f32_16x16x32_bf16(aA[4 + s], w[8 + s], aR0, 0, 0, 0);
                aR1 = __builtin_amdgcn_mfma_f32_16x16x32_bf16(aB[4 + s], w[8 + s], aR1, 0, 0, 0);
            }
        }
        {   // z gate
            bf16x8 w[12];
            #pragma unroll
            for (int s = 0; s < 8; ++s)
                w[s] = *(const bf16x8*)(smem + 32768 + ((cbI + s * 64) ^ sw));
            #pragma unroll
            for (int s = 0; s < 4; ++s)
                w[8 + s] = *(const bf16x8*)(smem + 98304 + 16384 + ((cbH + s * 64) ^ sw));
            #pragma unroll
            for (int s = 0; s < 8; ++s) {
                aZ0 = __builtin_amdgcn_mfma_f32_16x16x32_bf16(aA[s], w[s], aZ0, 0, 0, 0);
                aZ1 = __builtin_amdgcn_mfma_f32_16x16x32_bf16(aB[s], w[s], aZ1, 0, 0, 0);
            }
            #pragma unroll
            for (int s = 0; s < 4; ++s) {
                aZ0 = __builtin_amdgcn_mfma_f32_16x16x32_bf16(aA[4 + s], w[8 + s], aZ0, 0, 0, 0);
                aZ1 = __builtin_amdgcn_mfma_f32_16x16x32_bf16(aB[4 + s], w[8 + s], aZ1, 0, 0, 0);
            }
        }
        {   // n gate
            bf16x8 w[12];
            #pragma unroll
            for (int s = 0; s < 8; ++s)
                w[s] = *(const bf16x8*)(smem + 65536 + ((cbI + s * 64) ^ sw));
            #pragma unroll
            for (int s = 0; s < 4; ++s)
                w[8 + s] = *(const bf16x8*)(smem + 98304 + 32768 + ((cbH + s * 64) ^ sw));
            #pragma unroll
            for (int s = 0; s < 8; ++s) {
                aN0 = __builtin_amdgcn_mfma_f32_16x16x32_bf16(aA[s], w[s], aN0, 0, 0, 0);
                aN1 = __builtin_amdgcn_mfma_f32_16x16x32_bf16(aB[s], w[s], aN1, 0, 0, 0);
            }
            #pragma unroll
            for (int s = 0; s < 4; ++s) {
                aH0 = __builtin_amdgcn_mfma_f32_16x16x32_bf16(aA[4 + s], w[8 + s], aH0, 0, 0, 0);
                aH1 = __builtin_amdgcn_mfma_f32_16x16x32_bf16(aB[4 + s], w[8 + s], aH1, 0, 0, 0);
            }
        }

        float brz = bif[colg] + bhf[colg];
        float bzz = bif[128 + colg] + bhf[128 + colg];
        float bnx = bif[256 + colg];
        float bnh = bhf[256 + colg];

        #pragma unroll
        for (int ms = 0; ms < 2; ++ms) {
            #pragma unroll
            for (int r = 0; r < 4; ++r) {
                float vR = ms ? aR1[r] : aR0[r];
                float vZ = ms ? aZ1[r] : aZ0[r];
                float vN = ms ? aN1[r] : aN0[r];
                float vH = ms ? aH1[r] : aH0[r];
                int row = rbase + ms * 16 + qm * 4 + r;
                float rg = sigm(vR + brz);
                float z  = sigm(vZ + bzz);
                float ng = tanh_fast(vN + bnx + rg * (vH + bnh));
                float h  = bf2f(X[(size_t)row * 256 + 128 + colg]);
                float h0 = fmaxf((1.f - z) * ng + z * h, 0.f);
                if (row < N) {
                    if (isb) ((u16*)out)[(size_t)row * 128 + colg] = f2bf(h0);
                    else     ((float*)out)[(size_t)row * 128 + colg] = h0;
                }
                ss[ms * 4 + r] += h0 * h0;
            }
        }
    }

    #pragma unroll
    for (int i = 0; i < 8; ++i) {
        float s = ss[i];
        s += __shfl_xor(s, 1, 64);
        s += __shfl_xor(s, 2, 64);
        s += __shfl_xor(s, 4, 64);
        s += __shfl_xor(s, 8, 64);
        ss[i] = s;
    }
    if (qr == 0) {
        #pragma unroll
        for (int ms = 0; ms < 2; ++ms)
            #pragma unroll
            for (int r = 0; r < 4; ++r)
                ssb[(size_t)g * NpadX + rbase + ms * 16 + qm * 4 + r] = ss[ms * 4 + r];
    }
}

// K4 pass 2: in-place row L2-normalize of out using the two 64-col partials.
__global__ __launch_bounds__(256) void k_norm(
    void* __restrict__ out, const float* __restrict__ ssb,
    const int* __restrict__ flag, int N, int NpadX)
{
    int isb = flag[0];
    int tid = threadIdx.x;
    int wave = tid >> 6, lane = tid & 63;
    int row = blockIdx.x * 16 + wave * 4 + (lane >> 4);
    if (row >= N) return;
    int c8 = (lane & 15) * 8;
    float s = ssb[row] + ssb[(size_t)NpadX + row];
    float iv = 1.f / fmaxf(sqrtf(s), 1e-12f);
    if (isb) {
        u16* p = (u16*)out + (size_t)row * 128 + c8;
        bf16x8 v = *(const bf16x8*)p;
        bf16x8 o;
        #pragma unroll
        for (int j = 0; j < 8; ++j) o[j] = (short)f2bf(bf2f((u16)v[j]) * iv);
        *(bf16x8*)p = o;
    } else {
        float* p = (float*)out + (size_t)row * 128 + c8;
        float4 v0 = *(float4*)p, v1 = *(float4*)(p + 4);
        v0.x *= iv; v0.y *= iv; v0.z *= iv; v0.w *= iv;
        v1.x *= iv; v1.y *= iv; v1.z *= iv; v1.w *= iv;
        *(float4*)p = v0; *(float4*)(p + 4) = v1;
    }
}

extern "C" void kernel_launch(void* const* d_in, const int* in_sizes, int n_in,
                              void* d_out, int out_size, void* d_ws, size_t ws_size,
                              hipStream_t stream) {
    const void* ent     = d_in[0];
    const void* bias    = d_in[2];
    const void* onorm   = d_in[3];
    const void* W       = d_in[4];
    const void* w_ih    = d_in[5];
    const void* w_hh    = d_in[6];
    const void* b_ih    = d_in[7];
    const void* b_hh    = d_in[8];
    const void* node_id = d_in[9];
    const int*  esrc    = (const int*)d_in[10];
    const int*  edst    = (const int*)d_in[11];

    int N = in_sizes[2] / D;     // 100000
    int E = in_sizes[10];        // 1600000
    int NpadX = ((N + 255) / 256) * 256;

    int bshift = 8;
    while ((((N - 1) >> bshift) + 1) > 512) bshift++;
    int NB = ((N - 1) >> bshift) + 1;

    char* ws = (char*)d_ws;
    size_t o = 0;
    int*   flag = (int*)(ws + o);   o += 64;
    u16*   WTb  = (u16*)(ws + o);   o += 16384u * 2;
    u16*   Wihb = (u16*)(ws + o);   o += 98304u * 2;
    u16*   Whhb = (u16*)(ws + o);   o += 49152u * 2;
    float* bif  = (float*)(ws + o); o += 2048;
    float* bhf  = (float*)(ws + o); o += 2048;
    u16*   X    = (u16*)(ws + o);   o += (size_t)NpadX * 256 * 2;
    u16*   hW   = (u16*)(ws + o);   o += (size_t)N * D * 2;
    int*   bhist = (int*)(ws + o);  o += 512 * 4;
    int*   bstart = (int*)(ws + o); o += 514 * 4;
    int*   bcur  = (int*)(ws + o);  o += 512 * 4;
    int*   rowstart = (int*)(ws + o); o += ((size_t)N + 16) * 4;
    int*   sorted_src = (int*)(ws + o); o += (size_t)E * 4;
    u64*   ebuf = (u64*)X;              // aliases X (dead until k_seg)
    float* ssb = (float*)sorted_src;    // dead after k_seg

    int nchunk = NpadX / 256;
    int nA = (E + 8191) / 8192;

    k_detect<<<1, 64, 0, stream>>>(ent, node_id, flag, bhist);
    k_prep<<<643, 256, 0, stream>>>(w_ih, w_hh, b_ih, b_hh, W, flag,
                                    WTb, Wihb, Whhb, bif, bhf);
    k_gmm_mfma<<<(N + 63) / 64, 256, 0, stream>>>(ent, node_id, WTb, hW, flag, N);
    k_bhist<<<nA, 256, 0, stream>>>(edst, bhist, E, NB, bshift);
    k_bscan<<<1, 512, 0, stream>>>(bhist, bstart, bcur, rowstart, NB, N, E);
    k_afill<<<nA, 256, 0, stream>>>(esrc, edst, bcur, ebuf, E, NB, bshift);
    k_bfill<<<NB, 256, 0, stream>>>(ebuf, bstart, rowstart, sorted_src, N, bshift);
    // 8 col-slices x node-groups of 32; slice = blockIdx % 8 (XCD pin)
    k_seg<<<((N + 31) / 32) * 8, 256, 0, stream>>>(hW, rowstart, sorted_src, onorm, bias, X, flag, N);
    k_gru_mfma<<<nchunk * 2, 512, 0, stream>>>(X, Wihb, Whhb, bif, bhf, d_out, ssb, flag, N, NpadX);
    k_norm<<<(N + 15) / 16, 256, 0, stream>>>(d_out, ssb, flag, N, NpadX);
}

// Round 9
// 509.455 us; speedup vs baseline: 1.5579x; 1.5579x over previous
//
#include <hip/hip_runtime.h>
#include <hip/hip_bf16.h>

#define D 128

typedef unsigned short u16;
typedef unsigned int   u32;
typedef unsigned long long u64;
typedef short bf16x8 __attribute__((ext_vector_type(8)));
typedef float f32x4  __attribute__((ext_vector_type(4)));

__device__ __forceinline__ float bf2f(u16 u) {
    union { u32 i; float f; } v; v.i = ((u32)u) << 16; return v.f;
}
__device__ __forceinline__ float bflo(u32 p) {
    union { u32 i; float f; } v; v.i = p << 16; return v.f;
}
__device__ __forceinline__ float bfhi(u32 p) {
    union { u32 i; float f; } v; v.i = p & 0xffff0000u; return v.f;
}
__device__ __forceinline__ u16 f2bf(float f) {
    union { float f; u32 i; } v; v.f = f;
    return (u16)((v.i + 0x7fffu + ((v.i >> 16) & 1u)) >> 16);
}
__device__ __forceinline__ float ldf(const void* p, long i, int isb) {
    return isb ? bf2f(((const u16*)p)[i]) : ((const float*)p)[i];
}

__device__ __forceinline__ float sigm(float x) { return 1.0f / (1.0f + __expf(-x)); }
__device__ __forceinline__ float tanh_fast(float x) {
    float a = fabsf(x);
    float t = __expf(-2.0f * a);
    float r = (1.0f - t) / (1.0f + t);
    return copysignf(r, x);
}

__global__ void DRlocal_net_79173427135059_kernel() {}

// K-1: runtime dtype detection + zero the bucket histogram.
__global__ __launch_bounds__(64) void k_detect(const void* ent, const void* nid,
                                               int* flag, int* bhist) {
    int lane = threadIdx.x;
    for (int i = lane; i < 512; i += 64) bhist[i] = 0;
    float a = fabsf(bf2f(((const u16*)ent)[lane]));
    bool sane = (a >= 9.765625e-4f && a <= 64.0f);
    u64 m = __ballot(sane);
    u32 w = ((const u32*)nid)[lane];
    bool oddzero = ((lane & 1) == 0) || (w == 0u);
    u64 m2 = __ballot(oddzero);
    if (lane == 0) {
        flag[0] = (__popcll(m) >= 48) ? 1 : 0;
        flag[1] = (m2 == ~0ull) ? 1 : 0;
    }
}

// K0: WTb[j][k] = bf16(W[k][j]); GRU weights -> bf16 as-is; biases -> f32.
__global__ __launch_bounds__(256) void k_prep(
    const void* __restrict__ w_ih, const void* __restrict__ w_hh,
    const void* __restrict__ b_ih, const void* __restrict__ b_hh,
    const void* __restrict__ W, const int* __restrict__ flag,
    u16* __restrict__ WTb, u16* __restrict__ Wihb, u16* __restrict__ Whhb,
    float* __restrict__ bif, float* __restrict__ bhf)
{
    int isb = flag[0];
    int t = blockIdx.x * 256 + threadIdx.x;
    if (t < 16384) {
        int k = t >> 7, j = t & 127;
        u16 v = isb ? ((const u16*)W)[t] : f2bf(((const float*)W)[t]);
        WTb[j * 128 + k] = v;
        return;
    }
    int u = t - 16384;
    if (u < 98304) { Wihb[u] = isb ? ((const u16*)w_ih)[u] : f2bf(((const float*)w_ih)[u]); return; }
    int v = u - 98304;
    if (v < 49152) { Whhb[v] = isb ? ((const u16*)w_hh)[v] : f2bf(((const float*)w_hh)[v]); return; }
    int b = v - 49152;
    if (b < 384) { bif[b] = ldf(b_ih, b, isb); return; }
    int c = b - 384;
    if (c < 384) { bhf[c] = ldf(b_hh, c, isb); return; }
}

// K1: hW = gather(ent, node_id) @ W via MFMA. 64 nodes/block, wave = one 16-row m-tile.
__global__ __launch_bounds__(256) void k_gmm_mfma(
    const void* __restrict__ ent, const void* __restrict__ node_id,
    const u16* __restrict__ WTb, u16* __restrict__ hW,
    const int* __restrict__ flag, int N)
{
    int isb = flag[0], i64 = flag[1];
    int tid = threadIdx.x;
    int wave = tid >> 6, lane = tid & 63;
    int qm = lane >> 4, qr = lane & 15;
    int row0 = blockIdx.x * 64 + wave * 16;

    int rowA = row0 + qr; if (rowA >= N) rowA = N - 1;
    long nid = i64 ? (long)((const long long*)node_id)[rowA]
                   : (long)((const int*)node_id)[rowA];

    bf16x8 a[4];
    if (isb) {
        const u16* ep = (const u16*)ent + nid * 128 + qm * 8;
        #pragma unroll
        for (int s = 0; s < 4; ++s) a[s] = *(const bf16x8*)(ep + s * 32);
    } else {
        const float* ep = (const float*)ent + nid * 128 + qm * 8;
        #pragma unroll
        for (int s = 0; s < 4; ++s) {
            float4 f0 = *(const float4*)(ep + s * 32);
            float4 f1 = *(const float4*)(ep + s * 32 + 4);
            bf16x8 t;
            t[0] = (short)f2bf(f0.x); t[1] = (short)f2bf(f0.y);
            t[2] = (short)f2bf(f0.z); t[3] = (short)f2bf(f0.w);
            t[4] = (short)f2bf(f1.x); t[5] = (short)f2bf(f1.y);
            t[6] = (short)f2bf(f1.z); t[7] = (short)f2bf(f1.w);
            a[s] = t;
        }
    }

    int r0 = row0 + qm * 4;
    #pragma unroll
    for (int f = 0; f < 8; ++f) {
        f32x4 acc = {0.f, 0.f, 0.f, 0.f};
        const u16* wp = WTb + (size_t)(f * 16 + qr) * 128 + qm * 8;
        #pragma unroll
        for (int s = 0; s < 4; ++s) {
            bf16x8 b = *(const bf16x8*)(wp + s * 32);
            acc = __builtin_amdgcn_mfma_f32_16x16x32_bf16(a[s], b, acc, 0, 0, 0);
        }
        int col = f * 16 + qr;
        #pragma unroll
        for (int r = 0; r < 4; ++r) {
            int row = r0 + r;
            if (row < N) hW[(size_t)row * 128 + col] = f2bf(acc[r]);
        }
    }
}

// ---- Bucket CSR build ----
__global__ __launch_bounds__(256) void k_bhist(
    const int* __restrict__ edst, int* __restrict__ bhist,
    int E, int NB, int bshift)
{
    __shared__ int lcnt[512];
    int t = threadIdx.x;
    int e0 = blockIdx.x * 8192;
    for (int i = t; i < NB; i += 256) lcnt[i] = 0;
    __syncthreads();
    for (int i = t; i < 8192; i += 256) {
        int e = e0 + i;
        if (e < E) atomicAdd(&lcnt[edst[e] >> bshift], 1);
    }
    __syncthreads();
    for (int i = t; i < NB; i += 256) {
        int c = lcnt[i];
        if (c) atomicAdd(&bhist[i], c);
    }
}

__global__ __launch_bounds__(512) void k_bscan(
    const int* __restrict__ bhist, int* __restrict__ bstart,
    int* __restrict__ bcur, int* __restrict__ rowstart,
    int NB, int N, int E)
{
    __shared__ int sh[512];
    int t = threadIdx.x;
    int v = (t < NB) ? bhist[t] : 0;
    sh[t] = v;
    __syncthreads();
    #pragma unroll
    for (int off = 1; off < 512; off <<= 1) {
        int x = (t >= off) ? sh[t - off] : 0;
        __syncthreads();
        sh[t] += x;
        __syncthreads();
    }
    int excl = sh[t] - v;
    if (t < NB) { bstart[t] = excl; bcur[t] = excl; }
    if (t == 0) { bstart[NB] = E; rowstart[N] = E; }
}

// B3: block-aggregated scatter into bucket-ordered ebuf, u32-packed:
// entry = (src << bshift) | (dst & (2^bshift - 1)). Valid because
// N <= 2^(32 - bshift) here (N=100000 < 2^24 at bshift=8). Halves the
// ebuf write (12.8 -> 6.4 MB) and the k_bfill read.
__global__ __launch_bounds__(256) void k_afill(
    const int* __restrict__ esrc, const int* __restrict__ edst,
    int* __restrict__ bcur, u32* __restrict__ ebuf,
    int E, int NB, int bshift)
{
    __shared__ int lcnt[512];
    int t = threadIdx.x;
    int e0 = blockIdx.x * 8192;
    for (int i = t; i < NB; i += 256) lcnt[i] = 0;
    __syncthreads();
    for (int i = t; i < 8192; i += 256) {
        int e = e0 + i;
        if (e < E) atomicAdd(&lcnt[edst[e] >> bshift], 1);
    }
    __syncthreads();
    for (int b = t; b < NB; b += 256) {
        int c = lcnt[b];
        lcnt[b] = c ? atomicAdd(&bcur[b], c) : 0;
    }
    __syncthreads();
    u32 dmask = (1u << bshift) - 1u;
    for (int i = t; i < 8192; i += 256) {
        int e = e0 + i;
        if (e < E) {
            int d = edst[e];
            int pos = atomicAdd(&lcnt[d >> bshift], 1);
            ebuf[pos] = ((u32)esrc[e] << bshift) | ((u32)d & dmask);
        }
    }
}

__global__ __launch_bounds__(256) void k_bfill(
    const u32* __restrict__ ebuf, const int* __restrict__ bstart,
    int* __restrict__ rowstart, int* __restrict__ sorted_src,
    int N, int bshift)
{
    __shared__ int lcnt[1024];
    __shared__ int lscan[256];
    int b = blockIdx.x, t = threadIdx.x;
    int nodes = 1 << bshift;
    int per = nodes >> 8;
    int base = b << bshift;
    int beg = bstart[b], end = bstart[b + 1];
    u32 dmask = (1u << bshift) - 1u;

    for (int i = t; i < nodes; i += 256) lcnt[i] = 0;
    __syncthreads();
    for (int i = beg + t; i < end; i += 256) {
        int doff = (int)(ebuf[i] & dmask);
        atomicAdd(&lcnt[doff], 1);
    }
    __syncthreads();

    int myv[4]; int mysum = 0;
    #pragma unroll
    for (int j = 0; j < 4; ++j) {
        myv[j] = (j < per) ? lcnt[t * per + j] : 0;
        mysum += myv[j];
    }
    lscan[t] = mysum;
    __syncthreads();
    #pragma unroll
    for (int off = 1; off < 256; off <<= 1) {
        int x = (t >= off) ? lscan[t - off] : 0;
        __syncthreads();
        lscan[t] += x;
        __syncthreads();
    }
    int run = beg + lscan[t] - mysum;
    #pragma unroll
    for (int j = 0; j < 4; ++j) {
        if (j < per) {
            int idx = t * per + j;
            int node = base + idx;
            if (node < N) rowstart[node] = run;
            lcnt[idx] = run;
            run += myv[j];
        }
    }
    __syncthreads();
    for (int i = beg + t; i < end; i += 256) {
        u32 p = ebuf[i];
        int doff = (int)(p & dmask);
        int pos = atomicAdd(&lcnt[doff], 1);
        sorted_src[pos] = (int)(p >> bshift);
    }
}

// K3 (reverted to the proven R7 version): segment sum, 4 nodes/block,
// 64 lanes = full 256 B row per edge (coalesced), 8-deep gather unroll.
__global__ __launch_bounds__(256) void k_seg(
    const u16* __restrict__ hW, const int* __restrict__ rowstart,
    const int* __restrict__ sorted_src, const void* __restrict__ onorm,
    const void* __restrict__ bias, u16* __restrict__ X,
    const int* __restrict__ flag, int N)
{
    int isb = flag[0];
    int tid = threadIdx.x;
    int node = blockIdx.x * 4 + (tid >> 6);
    int lane = tid & 63;
    if (node >= N) return;
    int beg = rowstart[node], end = rowstart[node + 1];
    const u32* hw2 = (const u32*)hW;
    float a0 = 0.f, a1 = 0.f;
    int e = beg;
    for (; e + 8 <= end; e += 8) {
        int sI[8]; u32 vI[8];
        #pragma unroll
        for (int i = 0; i < 8; ++i) sI[i] = sorted_src[e + i];
        #pragma unroll
        for (int i = 0; i < 8; ++i) vI[i] = hw2[(size_t)sI[i] * 64 + lane];
        #pragma unroll
        for (int i = 0; i < 8; ++i) { a0 += bflo(vI[i]); a1 += bfhi(vI[i]); }
    }
    for (; e + 4 <= end; e += 4) {
        int s0 = sorted_src[e], s1 = sorted_src[e + 1];
        int s2 = sorted_src[e + 2], s3 = sorted_src[e + 3];
        u32 v0 = hw2[(size_t)s0 * 64 + lane];
        u32 v1 = hw2[(size_t)s1 * 64 + lane];
        u32 v2 = hw2[(size_t)s2 * 64 + lane];
        u32 v3 = hw2[(size_t)s3 * 64 + lane];
        a0 += bflo(v0) + bflo(v1) + bflo(v2) + bflo(v3);
        a1 += bfhi(v0) + bfhi(v1) + bfhi(v2) + bfhi(v3);
    }
    for (; e < end; ++e) {
        u32 v = hw2[(size_t)sorted_src[e] * 64 + lane];
        a0 += bflo(v); a1 += bfhi(v);
    }
    float on = ldf(onorm, node, isb);
    u32 p = ((u32)f2bf(a1 * on) << 16) | (u32)f2bf(a0 * on);
    ((u32*)X)[(size_t)node * 128 + lane] = p;
    u32 pb;
    if (isb) pb = ((const u32*)bias)[(size_t)node * 64 + lane];
    else {
        const float* bp = (const float*)bias + (size_t)node * 128 + lane * 2;
        pb = ((u32)f2bf(bp[1]) << 16) | (u32)f2bf(bp[0]);
    }
    ((u32*)X)[(size_t)node * 128 + 64 + lane] = pb;
}

// K4 v6, pass 1: LDS-weight-resident MFMA GRU, column-split (unchanged, proven).
__global__ __launch_bounds__(512, 2) void k_gru_mfma(
    const u16* __restrict__ X, const u16* __restrict__ Wih,
    const u16* __restrict__ Whh, const float* __restrict__ bif,
    const float* __restrict__ bhf, void* __restrict__ out,
    float* __restrict__ ssb,
    const int* __restrict__ flag, int N, int NpadX)
{
    __shared__ alignas(16) char smem[147456];
    int isb = flag[0];
    int tid = threadIdx.x;
    int wave = tid >> 6, lane = tid & 63;
    int qm = lane >> 4, qr = lane & 15;
    int g = blockIdx.x & 1;
    int chunk = blockIdx.x >> 1;
    int g64 = g * 64;

    for (int t = tid; t < 6144; t += 512) {
        int L = t * 16;
        int kb = L & 511;
        int c  = (L >> 9) & 63;
        int gi = L >> 15;
        int src = (gi * 128 + g64 + c) * 512 + kb;
        int dst = L ^ ((c & 7) << 4);
        *(bf16x8*)(smem + dst) = *(const bf16x8*)((const char*)Wih + src);
    }
    for (int t = tid; t < 3072; t += 512) {
        int L = t * 16;
        int kb = L & 255;
        int c  = (L >> 8) & 63;
        int gi = L >> 14;
        int src = (gi * 128 + g64 + c) * 256 + kb;
        int dst = 98304 + (L ^ ((c & 7) << 4));
        *(bf16x8*)(smem + dst) = *(const bf16x8*)((const char*)Whh + src);
    }
    __syncthreads();

    int rbase = chunk * 256 + wave * 32;

    bf16x8 aA[8], aB[8];
    {
        const u16* x0 = X + (size_t)(rbase + qr) * 256 + qm * 8;
        #pragma unroll
        for (int s = 0; s < 8; ++s) aA[s] = *(const bf16x8*)(x0 + s * 32);
        const u16* x1 = x0 + 16 * 256;
        #pragma unroll
        for (int s = 0; s < 8; ++s) aB[s] = *(const bf16x8*)(x1 + s * 32);
    }

    float ss[8] = {0.f, 0.f, 0.f, 0.f, 0.f, 0.f, 0.f, 0.f};

    #pragma unroll 1
    for (int sl = 0; sl < 4; ++sl) {
        int colIdx = sl * 16 + qr;
        int colg = g64 + colIdx;
        int sw = (qr & 7) << 4;
        int cbI = colIdx * 512 + qm * 16;
        int cbH = colIdx * 256 + qm * 16;

        f32x4 zz = {0.f, 0.f, 0.f, 0.f};
        f32x4 aR0 = zz, aR1 = zz, aZ0 = zz, aZ1 = zz;
        f32x4 aN0 = zz, aN1 = zz, aH0 = zz, aH1 = zz;

        {   // r gate
            bf16x8 w[12];
            #pragma unroll
            for (int s = 0; s < 8; ++s)
                w[s] = *(const bf16x8*)(smem + ((cbI + s * 64) ^ sw));
            #pragma unroll
            for (int s = 0; s < 4; ++s)
                w[8 + s] = *(const bf16x8*)(smem + 98304 + ((cbH + s * 64) ^ sw));
            #pragma unroll
            for (int s = 0; s < 8; ++s) {
                aR0 = __builtin_amdgcn_mfma_f32_16x16x32_bf16(aA[s], w[s], aR0, 0, 0, 0);
                aR1 = __builtin_amdgcn_mfma_f32_16x16x32_bf16(aB[s], w[s], aR1, 0, 0, 0);
            }
            #pragma unroll
            for (int s = 0; s < 4; ++s) {
                aR0 = __builtin_amdgcn_mfma_f32_16x16x32_bf16(aA[4 + s], w[8 + s], aR0, 0, 0, 0);
                aR1 = __builtin_amdgcn_mfma_f32_16x16x32_bf16(aB[4 + s], w[8 + s], aR1, 0, 0, 0);
            }
        }
        {   // z gate
            bf16x8 w[12];
            #pragma unroll
            for (int s = 0; s < 8; ++s)
                w[s] = *(const bf16x8*)(smem + 32768 + ((cbI + s * 64) ^ sw));
            #pragma unroll
            for (int s = 0; s < 4; ++s)
                w[8 + s] = *(const bf16x8*)(smem + 98304 + 16384 + ((cbH + s * 64) ^ sw));
            #pragma unroll
            for (int s = 0; s < 8; ++s) {
                aZ0 = __builtin_amdgcn_mfma_f32_16x16x32_bf16(aA[s], w[s], aZ0, 0, 0, 0);
                aZ1 = __builtin_amdgcn_mfma_f32_16x16x32_bf16(aB[s], w[s], aZ1, 0, 0, 0);
            }
            #pragma unroll
            for (int s = 0; s < 4; ++s) {
                aZ0 = __builtin_amdgcn_mfma_f32_16x16x32_bf16(aA[4 + s], w[8 + s], aZ0, 0, 0, 0);
                aZ1 = __builtin_amdgcn_mfma_f32_16x16x32_bf16(aB[4 + s], w[8 + s], aZ1, 0, 0, 0);
            }
        }
        {   // n gate
            bf16x8 w[12];
            #pragma unroll
            for (int s = 0; s < 8; ++s)
                w[s] = *(const bf16x8*)(smem + 65536 + ((cbI + s * 64) ^ sw));
            #pragma unroll
            for (int s = 0; s < 4; ++s)
                w[8 + s] = *(const bf16x8*)(smem + 98304 + 32768 + ((cbH + s * 64) ^ sw));
            #pragma unroll
            for (int s = 0; s < 8; ++s) {
                aN0 = __builtin_amdgcn_mfma_f32_16x16x32_bf16(aA[s], w[s], aN0, 0, 0, 0);
                aN1 = __builtin_amdgcn_mfma_f32_16x16x32_bf16(aB[s], w[s], aN1, 0, 0, 0);
            }
            #pragma unroll
            for (int s = 0; s < 4; ++s) {
                aH0 = __builtin_amdgcn_mfma_f32_16x16x32_bf16(aA[4 + s], w[8 + s], aH0, 0, 0, 0);
                aH1 = __builtin_amdgcn_mfma_f32_16x16x32_bf16(aB[4 + s], w[8 + s], aH1, 0, 0, 0);
            }
        }

        float brz = bif[colg] + bhf[colg];
        float bzz = bif[128 + colg] + bhf[128 + colg];
        float bnx = bif[256 + colg];
        float bnh = bhf[256 + colg];

        #pragma unroll
        for (int ms = 0; ms < 2; ++ms) {
            #pragma unroll
            for (int r = 0; r < 4; ++r) {
                float vR = ms ? aR1[r] : aR0[r];
                float vZ = ms ? aZ1[r] : aZ0[r];
                float vN = ms ? aN1[r] : aN0[r];
                float vH = ms ? aH1[r] : aH0[r];
                int row = rbase + ms * 16 + qm * 4 + r;
                float rg = sigm(vR + brz);
                float z  = sigm(vZ + bzz);
                float ng = tanh_fast(vN + bnx + rg * (vH + bnh));
                float h  = bf2f(X[(size_t)row * 256 + 128 + colg]);
                float h0 = fmaxf((1.f - z) * ng + z * h, 0.f);
                if (row < N) {
                    if (isb) ((u16*)out)[(size_t)row * 128 + colg] = f2bf(h0);
                    else     ((float*)out)[(size_t)row * 128 + colg] = h0;
                }
                ss[ms * 4 + r] += h0 * h0;
            }
        }
    }

    #pragma unroll
    for (int i = 0; i < 8; ++i) {
        float s = ss[i];
        s += __shfl_xor(s, 1, 64);
        s += __shfl_xor(s, 2, 64);
        s += __shfl_xor(s, 4, 64);
        s += __shfl_xor(s, 8, 64);
        ss[i] = s;
    }
    if (qr == 0) {
        #pragma unroll
        for (int ms = 0; ms < 2; ++ms)
            #pragma unroll
            for (int r = 0; r < 4; ++r)
                ssb[(size_t)g * NpadX + rbase + ms * 16 + qm * 4 + r] = ss[ms * 4 + r];
    }
}

// K4 pass 2: in-place row L2-normalize of out using the two 64-col partials.
__global__ __launch_bounds__(256) void k_norm(
    void* __restrict__ out, const float* __restrict__ ssb,
    const int* __restrict__ flag, int N, int NpadX)
{
    int isb = flag[0];
    int tid = threadIdx.x;
    int wave = tid >> 6, lane = tid & 63;
    int row = blockIdx.x * 16 + wave * 4 + (lane >> 4);
    if (row >= N) return;
    int c8 = (lane & 15) * 8;
    float s = ssb[row] + ssb[(size_t)NpadX + row];
    float iv = 1.f / fmaxf(sqrtf(s), 1e-12f);
    if (isb) {
        u16* p = (u16*)out + (size_t)row * 128 + c8;
        bf16x8 v = *(const bf16x8*)p;
        bf16x8 o;
        #pragma unroll
        for (int j = 0; j < 8; ++j) o[j] = (short)f2bf(bf2f((u16)v[j]) * iv);
        *(bf16x8*)p = o;
    } else {
        float* p = (float*)out + (size_t)row * 128 + c8;
        float4 v0 = *(float4*)p, v1 = *(float4*)(p + 4);
        v0.x *= iv; v0.y *= iv; v0.z *= iv; v0.w *= iv;
        v1.x *= iv; v1.y *= iv; v1.z *= iv; v1.w *= iv;
        *(float4*)p = v0; *(float4*)(p + 4) = v1;
    }
}

extern "C" void kernel_launch(void* const* d_in, const int* in_sizes, int n_in,
                              void* d_out, int out_size, void* d_ws, size_t ws_size,
                              hipStream_t stream) {
    const void* ent     = d_in[0];
    const void* bias    = d_in[2];
    const void* onorm   = d_in[3];
    const void* W       = d_in[4];
    const void* w_ih    = d_in[5];
    const void* w_hh    = d_in[6];
    const void* b_ih    = d_in[7];
    const void* b_hh    = d_in[8];
    const void* node_id = d_in[9];
    const int*  esrc    = (const int*)d_in[10];
    const int*  edst    = (const int*)d_in[11];

    int N = in_sizes[2] / D;     // 100000
    int E = in_sizes[10];        // 1600000
    int NpadX = ((N + 255) / 256) * 256;

    int bshift = 8;
    while ((((N - 1) >> bshift) + 1) > 512) bshift++;
    int NB = ((N - 1) >> bshift) + 1;

    char* ws = (char*)d_ws;
    size_t o = 0;
    int*   flag = (int*)(ws + o);   o += 64;
    u16*   WTb  = (u16*)(ws + o);   o += 16384u * 2;
    u16*   Wihb = (u16*)(ws + o);   o += 98304u * 2;
    u16*   Whhb = (u16*)(ws + o);   o += 49152u * 2;
    float* bif  = (float*)(ws + o); o += 2048;
    float* bhf  = (float*)(ws + o); o += 2048;
    u16*   X    = (u16*)(ws + o);   o += (size_t)NpadX * 256 * 2;
    u16*   hW   = (u16*)(ws + o);   o += (size_t)N * D * 2;
    int*   bhist = (int*)(ws + o);  o += 512 * 4;
    int*   bstart = (int*)(ws + o); o += 514 * 4;
    int*   bcur  = (int*)(ws + o);  o += 512 * 4;
    int*   rowstart = (int*)(ws + o); o += ((size_t)N + 16) * 4;
    int*   sorted_src = (int*)(ws + o); o += (size_t)E * 4;
    u32*   ebuf = (u32*)X;              // aliases X (dead until k_seg)
    float* ssb = (float*)sorted_src;    // dead after k_seg

    int nchunk = NpadX / 256;
    int nA = (E + 8191) / 8192;

    k_detect<<<1, 64, 0, stream>>>(ent, node_id, flag, bhist);
    k_prep<<<643, 256, 0, stream>>>(w_ih, w_hh, b_ih, b_hh, W, flag,
                                    WTb, Wihb, Whhb, bif, bhf);
    k_gmm_mfma<<<(N + 63) / 64, 256, 0, stream>>>(ent, node_id, WTb, hW, flag, N);
    k_bhist<<<nA, 256, 0, stream>>>(edst, bhist, E, NB, bshift);
    k_bscan<<<1, 512, 0, stream>>>(bhist, bstart, bcur, rowstart, NB, N, E);
    k_afill<<<nA, 256, 0, stream>>>(esrc, edst, bcur, ebuf, E, NB, bshift);
    k_bfill<<<NB, 256, 0, stream>>>(ebuf, bstart, rowstart, sorted_src, N, bshift);
    k_seg<<<(N + 3) / 4, 256, 0, stream>>>(hW, rowstart, sorted_src, onorm, bias, X, flag, N);
    k_gru_mfma<<<nchunk * 2, 512, 0, stream>>>(X, Wihb, Whhb, bif, bhf, d_out, ssb, flag, N, NpadX);
    k_norm<<<(N + 15) / 16, 256, 0, stream>>>(d_out, ssb, flag, N, NpadX);
}